// Round 11
// baseline (1567.887 us; speedup 1.0000x reference)
//
#include <hip/hip_runtime.h>
#include <cstdint>

#define B_    512
#define T_    64
#define VOCAB_ 10000
#define VPAD_ 10112     // vocab padded to 128
#define EMB_  512
#define HID_  1024
#define G4H_  4096      // 4*HID
#define KCAT_ 1536      // EMB + HID
#define NIMG_ 2048

typedef _Float16 half8 __attribute__((ext_vector_type(8)));
typedef _Float16 half4 __attribute__((ext_vector_type(4)));
typedef _Float16 half2v __attribute__((ext_vector_type(2)));
typedef float floatx4 __attribute__((ext_vector_type(4)));

// Async global->LDS, 16B per lane. LDS dest = wave-uniform base (HW adds
// lane*16). Per-lane SOURCE address is free (gather OK).
__device__ __forceinline__ void async_copy16(void* lds_uniform, const void* gsrc) {
    __builtin_amdgcn_global_load_lds(
        (__attribute__((address_space(1))) void*)(uintptr_t)gsrc,
        (__attribute__((address_space(3))) void*)(uint32_t)(uintptr_t)lds_uniform,
        16, 0, 0);
}

__device__ __forceinline__ float fsig(float x)  { return 1.0f / (1.0f + __expf(-x)); }
__device__ __forceinline__ float ftanh(float x) { return 1.0f - 2.0f / (__expf(2.0f * x) + 1.0f); }

// R10 32-col permutation: n_perm = q*32 + gate*8 + u  (q = j>>3, u = j&7)
//   -> n_orig = gate*HID + q*8 + u.
// A 32-col block tile (q fixed per by? no: by covers q=by) holds all 4 gates
// of 8 j's. In a 16-col MFMA frag pair, lanes (lcol, lcol^8) hold (i,g)/(f,o)
// of the same j -> epilogue completes with shfl_xor(8).
// PE pack order pp: i->0, g->1, f->2, o->3 (so (i,g) and (f,o) are 4B pairs).

// ---------------------------------------------------------------------------
// One-time: emb->f16, Wc16 = permuted [W_ih|W_hh] (4096 x 1536), Wout16,
// biasp = permuted (b_ih+b_hh), Hseq[0] = 0, tokperm[t*B+b] = m[b][t].
// ---------------------------------------------------------------------------
__global__ __launch_bounds__(256) void convert_kernel(
    const int* __restrict__ m, const float* __restrict__ emb,
    const float* __restrict__ W_ih, const float* __restrict__ W_hh,
    const float* __restrict__ b_ih, const float* __restrict__ b_hh,
    const float* __restrict__ W_out,
    _Float16* __restrict__ emb16, _Float16* __restrict__ Wc16,
    _Float16* __restrict__ Wout16, float* __restrict__ biasp,
    _Float16* __restrict__ Hseq, int* __restrict__ tokperm)
{
    const long long EMB_N = (long long)VOCAB_ * EMB_;
    const long long WC_N  = (long long)G4H_ * KCAT_;
    const long long WO_N  = (long long)NIMG_ * HID_;
    const long long BI_N  = G4H_;
    const long long ST_N  = (long long)B_ * HID_;
    const long long TK_N  = (long long)B_ * T_;

    long long i = (long long)blockIdx.x * 256 + threadIdx.x;
    if (i < EMB_N) { emb16[i] = (_Float16)emb[i]; return; }
    i -= EMB_N;
    if (i < WC_N) {
        int n_perm = (int)(i / KCAT_);
        int k      = (int)(i % KCAT_);
        int q    = n_perm >> 5;
        int gate = (n_perm >> 3) & 3;
        int u    = n_perm & 7;
        int n_orig = gate * HID_ + q * 8 + u;
        float v = (k < EMB_) ? W_ih[(size_t)n_orig * EMB_ + k]
                             : W_hh[(size_t)n_orig * HID_ + (k - EMB_)];
        Wc16[i] = (_Float16)v;
        return;
    }
    i -= WC_N;
    if (i < WO_N) { Wout16[i] = (_Float16)W_out[i]; return; }
    i -= WO_N;
    if (i < BI_N) {
        int n_perm = (int)i;
        int q    = n_perm >> 5;
        int gate = (n_perm >> 3) & 3;
        int u    = n_perm & 7;
        biasp[i] = b_ih[gate * HID_ + q * 8 + u] + b_hh[gate * HID_ + q * 8 + u];
        return;
    }
    i -= BI_N;
    if (i < ST_N) { Hseq[i] = (_Float16)0.0f; return; }   // Hseq[0] = h_0 = 0
    i -= ST_N;
    if (i < TK_N) {
        int t = (int)(i / B_), b = (int)(i % B_);
        tokperm[i] = m[(size_t)b * T_ + t];
    }
}

// ---------------------------------------------------------------------------
// PE table GEMM: PEx[v][q*32 + u*4 + pp] = emb[v] @ W_ih_perm^T + biasp,
// pp order i,g,f,o. Lane's (i,g) or (f,o) pair is one 4B half2.
// ---------------------------------------------------------------------------
__global__ __launch_bounds__(256) void gemm_pe(
    const _Float16* __restrict__ emb16, const _Float16* __restrict__ Wc16,
    const float* __restrict__ biasp, _Float16* __restrict__ PEx)
{
    __shared__ __align__(16) _Float16 As[128 * 32];
    __shared__ __align__(16) _Float16 Bs[128 * 32];

    const int tid  = threadIdx.x;
    const int wid  = tid >> 6;
    const int lane = tid & 63;
    const int lcol = lane & 15;
    const int quad = lane >> 4;
    const int wm   = wid >> 1;
    const int wn   = wid & 1;

    const int r0 = blockIdx.x * 128;
    const int n0 = blockIdx.y * 128;

    floatx4 acc[4][4];
#pragma unroll
    for (int i = 0; i < 4; ++i)
#pragma unroll
        for (int j = 0; j < 4; ++j) acc[i][j] = (floatx4){0.f, 0.f, 0.f, 0.f};

    const int ar = tid >> 2;
    const int kq = tid & 3;

    for (int k0 = 0; k0 < EMB_; k0 += 32) {
        async_copy16((char*)As + (wid << 10),
                     emb16 + (size_t)(r0 + ar) * EMB_ + (k0 + kq * 8));
        async_copy16((char*)As + 4096 + (wid << 10),
                     emb16 + (size_t)(r0 + 64 + ar) * EMB_ + (k0 + kq * 8));
        async_copy16((char*)Bs + (wid << 10),
                     Wc16 + (size_t)(n0 + ar) * KCAT_ + (k0 + kq * 8));
        async_copy16((char*)Bs + 4096 + (wid << 10),
                     Wc16 + (size_t)(n0 + 64 + ar) * KCAT_ + (k0 + kq * 8));
        __syncthreads();

        half8 af[4], bf[4];
#pragma unroll
        for (int mi = 0; mi < 4; ++mi)
            af[mi] = *(const half8*)&As[(wm * 64 + mi * 16 + lcol) * 32 + quad * 8];
#pragma unroll
        for (int ni = 0; ni < 4; ++ni)
            bf[ni] = *(const half8*)&Bs[(wn * 64 + ni * 16 + lcol) * 32 + quad * 8];
#pragma unroll
        for (int mi = 0; mi < 4; ++mi)
#pragma unroll
            for (int ni = 0; ni < 4; ++ni)
                acc[mi][ni] = __builtin_amdgcn_mfma_f32_16x16x32_f16(
                    af[mi], bf[ni], acc[mi][ni], 0, 0, 0);
        __syncthreads();
    }

    // Epilogue: cols base+lcol (gate 0/1) and base+16+lcol (gate 2/3) share
    // (q, u); their pp slots are (lcol>=8 ? 2 : 0) and +1 -> one half2 store.
    const int u   = lcol & 7;
    const int pp0 = (lcol >= 8) ? 2 : 0;
    float bv[4];
#pragma unroll
    for (int ni = 0; ni < 4; ++ni) bv[ni] = biasp[n0 + wn * 64 + ni * 16 + lcol];
#pragma unroll
    for (int mi = 0; mi < 4; ++mi) {
#pragma unroll
        for (int r = 0; r < 4; ++r) {
            const int row = r0 + wm * 64 + mi * 16 + quad * 4 + r;
#pragma unroll
            for (int nip = 0; nip < 2; ++nip) {   // col-frag pairs (0,1),(2,3)
                const int q = (n0 + wn * 64 + nip * 32) >> 5;
                half2v v;
                v[0] = (_Float16)(acc[mi][2 * nip][r]     + bv[2 * nip]);
                v[1] = (_Float16)(acc[mi][2 * nip + 1][r] + bv[2 * nip + 1]);
                *(half2v*)(PEx + (size_t)row * G4H_ + q * 32 + u * 4 + pp0) = v;
            }
        }
    }
}

// ---------------------------------------------------------------------------
// Persistent LSTM. Grid (4,128) = 512 blocks, 2/CU (launch_bounds(256,2),
// LDS 64.3 KB). Tile 128 rows x 32 perm-cols; wave = 32 rows x 32 cols.
// R10 vs R9: doubled blocks/CU so poll/latency stalls of one block overlap
// the other block's compute (R9 Occupancy was 12%: 1 wave/SIMD, stalls fully
// exposed). W per block halves to 64 KB (loaded once, frag-major,
// conflict-free). Epilogue gate-exchange via shfl_xor(8) lane pairs.
// Sync = R9's proven zero-fence freshness scheme + two-phase wait.
// ---------------------------------------------------------------------------
__global__ __launch_bounds__(256, 2) void lstm_persistent(
    const _Float16* __restrict__ PEx, const int* __restrict__ tokperm,
    const _Float16* __restrict__ Wc16,
    _Float16* __restrict__ Hseq,
    unsigned* __restrict__ flags)
{
    __shared__ __align__(16) char Wlds[65536];   // frag-major, 64 KB

    const int tid  = threadIdx.x;
    const int wid  = tid >> 6;
    const int lane = tid & 63;
    const int lcol = lane & 15;
    const int quad = lane >> 4;
    const int bx   = blockIdx.x;      // 0..3
    const int b0   = bx * 128;
    const int by   = blockIdx.y;      // 0..127 (q = by)
    const int n0   = by * 32;
    const int rot  = (by & 1) * 16;   // chunk rotation (wave-uniform)
    const int u    = lcol & 7;
    const int pp0  = (lcol >= 8) ? 2 : 0;

    // One-time cross-launch safety: clear any stale lines (cheap, once).
    __builtin_amdgcn_fence(__ATOMIC_ACQUIRE, "agent");

    // ---- W one-time load, fragment-major: Wlds[((s*2+ni)*64+lane)*16] holds
    // B-frag W[n0+ni*16+lcol][EMB + s*32+quad*8..+7]. Wave wid covers
    // s in [wid*8, wid*8+8). Conflict-free by construction.
    for (int si = 0; si < 8; ++si) {
        const int s = wid * 8 + si;
#pragma unroll
        for (int ni = 0; ni < 2; ++ni) {
            half8 v = *(const half8*)(Wc16 + (size_t)(n0 + ni * 16 + lcol) * KCAT_
                                      + EMB_ + s * 32 + quad * 8);
            *(half8*)(Wlds + (((s * 2 + ni) << 6) + lane) * 16) = v;
        }
    }

    // Thread's cells: rows wid*32+mi*16+quad*4+r (mi 0..1), j = by*8+u.
    // Lane pair (lcol, lcol^8) duplicates each cell (identical math).
    float cst[2][4] = {{0.f, 0.f, 0.f, 0.f}, {0.f, 0.f, 0.f, 0.f}};
    half2v pe[2][4];

    // PE prefetch for t=0 (one 4B load per (mi,r))
#pragma unroll
    for (int mi = 0; mi < 2; ++mi)
#pragma unroll
        for (int r = 0; r < 4; ++r) {
            const int row = wid * 32 + mi * 16 + quad * 4 + r;
            const int tk = tokperm[b0 + row];
            pe[mi][r] = *(const half2v*)(PEx + (size_t)tk * G4H_ + by * 32 + u * 4 + pp0);
        }

    __syncthreads();  // W in LDS visible to all waves

    const int wrow = wid * 32;
    const int gA = rot >> 4;   // phase-A flag group (64 producers each)

    for (int t = 0; t < T_; ++t) {
        const _Float16* h_prev = Hseq + (size_t)t * (B_ * HID_);
        _Float16*       h_next = Hseq + (size_t)(t + 1) * (B_ * HID_);

        const unsigned want = 0x5AB00000u + (unsigned)(t - 1);
        const unsigned* f = flags + ((size_t)(t > 0 ? t - 1 : 0) * 4 + bx) * 128;

        // wait for flag group g (producers by' = g*64 + lane); relaxed spin.
        auto waitg = [&](int g) {
            if (t == 0) return;
            while (!__all((int)(__hip_atomic_load(&f[g * 64 + lane], __ATOMIC_RELAXED,
                                                  __HIP_MEMORY_SCOPE_AGENT) == want)))
                __builtin_amdgcn_s_sleep(1);
            asm volatile("" ::: "memory");  // no hoisting of h loads above poll
        };

        // A-fragment source rows (plain cached loads on FRESH lines)
        const _Float16* arow0 = h_prev + (size_t)(b0 + wrow + lcol) * HID_ + quad * 8;
        const _Float16* arow1 = arow0 + (size_t)16 * HID_;

        floatx4 acc[2][2];
#pragma unroll
        for (int mi = 0; mi < 2; ++mi)
#pragma unroll
            for (int r = 0; r < 4; ++r) {
                acc[mi][0][r] = (float)pe[mi][r][0];   // gate lcol>>3 (i|f)
                acc[mi][1][r] = (float)pe[mi][r][1];   // gate 2+(lcol>>3) (g|o)
            }

        // ---- phase A wait, prime pipeline on first-half chunks ----
        waitg(gA);
        half8 pa0[8], pa1[8];
#pragma unroll
        for (int c = 0; c < 8; ++c) {
            const int cs = (c + rot) & 31;
            pa0[c] = *(const half8*)(arow0 + cs * 32);
            pa1[c] = *(const half8*)(arow1 + cs * 32);
        }
        // ---- phase B wait (16 loads already in flight) ----
        waitg(1 - gA);

        // ---- straight depth-8 pipeline over 32 k32 iters ----
#pragma unroll
        for (int s = 0; s < 32; ++s) {
            const int cs = (s + rot) & 31;
            const half8 a0 = pa0[s & 7];
            const half8 a1 = pa1[s & 7];
            if (s + 8 < 32) {
                const int cs8 = (s + 8 + rot) & 31;
                pa0[s & 7] = *(const half8*)(arow0 + cs8 * 32);
                pa1[s & 7] = *(const half8*)(arow1 + cs8 * 32);
            }
            const half8 bw0 = *(const half8*)(Wlds + (((cs * 2 + 0) << 6) + lane) * 16);
            const half8 bw1 = *(const half8*)(Wlds + (((cs * 2 + 1) << 6) + lane) * 16);
            acc[0][0] = __builtin_amdgcn_mfma_f32_16x16x32_f16(a0, bw0, acc[0][0], 0, 0, 0);
            acc[0][1] = __builtin_amdgcn_mfma_f32_16x16x32_f16(a0, bw1, acc[0][1], 0, 0, 0);
            acc[1][0] = __builtin_amdgcn_mfma_f32_16x16x32_f16(a1, bw0, acc[1][0], 0, 0, 0);
            acc[1][1] = __builtin_amdgcn_mfma_f32_16x16x32_f16(a1, bw1, acc[1][1], 0, 0, 0);
        }

        // ---- fused LSTM cell: lane pair (lcol, lcol^8) exchanges gates via
        // shfl_xor(8); both lanes compute the cell (identical, deterministic);
        // lcol<8 stores h (2B relaxed agent atomic = write-through to LLC) ----
#pragma unroll
        for (int mi = 0; mi < 2; ++mi)
#pragma unroll
            for (int r = 0; r < 4; ++r) {
                const float own0 = acc[mi][0][r];
                const float own1 = acc[mi][1][r];
                const float oth0 = __shfl_xor(own0, 8);
                const float oth1 = __shfl_xor(own1, 8);
                const float iv = fsig((lcol < 8) ? own0 : oth0);
                const float gv = ftanh((lcol < 8) ? own1 : oth1);
                const float fv = fsig((lcol < 8) ? oth0 : own0);
                const float ov = fsig((lcol < 8) ? oth1 : own1);
                cst[mi][r] = fv * cst[mi][r] + iv * gv;
                const float hval = ov * ftanh(cst[mi][r]);
                if (lcol < 8) {
                    const int row = wrow + mi * 16 + quad * 4 + r;
                    const _Float16 hv = (_Float16)hval;
                    unsigned short us = __builtin_bit_cast(unsigned short, hv);
                    __hip_atomic_store(
                        (unsigned short*)&h_next[(size_t)(b0 + row) * HID_ + by * 8 + u],
                        us, __ATOMIC_RELAXED, __HIP_MEMORY_SCOPE_AGENT);
                }
            }

        // ---- publish: drain stores (syncthreads waits vmcnt 0), then one
        // relaxed flag store by tid0. NO fences. ----
        __syncthreads();
        if (tid == 0) {
            __hip_atomic_store(&flags[((size_t)t * 4 + bx) * 128 + by],
                               0x5AB00000u + (unsigned)t,
                               __ATOMIC_RELAXED, __HIP_MEMORY_SCOPE_AGENT);
        }

        // PE prefetch for t+1 (read-only cached data; overlaps others' polls)
        if (t + 1 < T_) {
#pragma unroll
            for (int mi = 0; mi < 2; ++mi)
#pragma unroll
                for (int r = 0; r < 4; ++r) {
                    const int row = wrow + mi * 16 + quad * 4 + r;
                    const int tk = tokperm[(t + 1) * B_ + b0 + row];
                    pe[mi][r] = *(const half2v*)(PEx + (size_t)tk * G4H_ + by * 32 + u * 4 + pp0);
                }
        }
    }
}

// ---------------------------------------------------------------------------
// Final projection GEMM (unpermuted): Out = h @ Wout16^T + b_out
// ---------------------------------------------------------------------------
__global__ __launch_bounds__(256) void gemm_out(
    const _Float16* __restrict__ A, const _Float16* __restrict__ Bw,
    const float* __restrict__ bias, float* __restrict__ Out, int N, int K)
{
    __shared__ __align__(16) _Float16 As[64 * 32];
    __shared__ __align__(16) _Float16 Bs[128 * 32];

    const int tid  = threadIdx.x;
    const int wid  = tid >> 6;
    const int lane = tid & 63;
    const int lcol = lane & 15;
    const int quad = lane >> 4;
    const int wm   = wid >> 1;
    const int wn   = wid & 1;

    const int b0 = blockIdx.x * 64;
    const int n0 = blockIdx.y * 128;

    floatx4 acc[2][4];
#pragma unroll
    for (int i = 0; i < 2; ++i)
#pragma unroll
        for (int j = 0; j < 4; ++j) acc[i][j] = (floatx4){0.f, 0.f, 0.f, 0.f};

    const int ar = tid >> 2;
    const int kq = tid & 3;

    for (int k0 = 0; k0 < K; k0 += 32) {
        async_copy16((char*)As + (wid << 10), A + (size_t)(b0 + ar) * K + (k0 + kq * 8));
        async_copy16((char*)Bs + (wid << 10), Bw + (size_t)(n0 + ar) * K + (k0 + kq * 8));
        async_copy16((char*)Bs + 4096 + (wid << 10),
                     Bw + (size_t)(n0 + 64 + ar) * K + (k0 + kq * 8));
        __syncthreads();

        half8 af[2], bfr[4];
#pragma unroll
        for (int mi = 0; mi < 2; ++mi)
            af[mi] = *(const half8*)&As[(wm * 32 + mi * 16 + lcol) * 32 + quad * 8];
#pragma unroll
        for (int ni = 0; ni < 4; ++ni)
            bfr[ni] = *(const half8*)&Bs[(wn * 64 + ni * 16 + lcol) * 32 + quad * 8];
#pragma unroll
        for (int mi = 0; mi < 2; ++mi)
#pragma unroll
            for (int ni = 0; ni < 4; ++ni)
                acc[mi][ni] = __builtin_amdgcn_mfma_f32_16x16x32_f16(
                    af[mi], bfr[ni], acc[mi][ni], 0, 0, 0);
        __syncthreads();
    }

#pragma unroll
    for (int mi = 0; mi < 2; ++mi) {
#pragma unroll
        for (int ni = 0; ni < 4; ++ni) {
            const int row = b0 + wm * 32 + mi * 16 + quad * 4;
            const int col = n0 + wn * 64 + ni * 16 + lcol;
            const float bv = bias[col];
#pragma unroll
            for (int r = 0; r < 4; ++r)
                Out[(size_t)(row + r) * N + col] = acc[mi][ni][r] + bv;
        }
    }
}

// ---------------------------------------------------------------------------
extern "C" void kernel_launch(void* const* d_in, const int* in_sizes, int n_in,
                              void* d_out, int out_size, void* d_ws, size_t ws_size,
                              hipStream_t stream)
{
    const int*   m     = (const int*)d_in[0];
    const float* emb   = (const float*)d_in[1];
    const float* W_ih  = (const float*)d_in[2];
    const float* W_hh  = (const float*)d_in[3];
    const float* b_ih  = (const float*)d_in[4];
    const float* b_hh  = (const float*)d_in[5];
    const float* W_out = (const float*)d_in[6];
    const float* b_out = (const float*)d_in[7];
    float* out = (float*)d_out;

    char* w = (char*)d_ws;
    size_t off = 0;
    auto alloc = [&](size_t bytes) {
        char* p = w + off;
        off = (off + bytes + 255) & ~(size_t)255;
        return p;
    };
    _Float16* emb16   = (_Float16*)alloc((size_t)VPAD_ * EMB_ * 2);
    _Float16* Wc16    = (_Float16*)alloc((size_t)G4H_ * KCAT_ * 2);
    _Float16* Wout16  = (_Float16*)alloc((size_t)NIMG_ * HID_ * 2);
    float*    biasp   = (float*)   alloc((size_t)G4H_ * 4);
    _Float16* Hseq    = (_Float16*)alloc((size_t)(T_ + 1) * B_ * HID_ * 2);  // 68 MB
    int*      tokperm = (int*)     alloc((size_t)B_ * T_ * 4);
    unsigned* flags   = (unsigned*)alloc((size_t)T_ * 4 * 128 * 4);  // 128 KB
    _Float16* PEx     = (_Float16*)alloc((size_t)VPAD_ * G4H_ * 2);  // 83 MB

    // 1) convert / permute / init (flags stay poisoned: magic differs per t)
    {
        const long long total = (long long)VOCAB_ * EMB_ + (long long)G4H_ * KCAT_ +
                                (long long)NIMG_ * HID_ + G4H_ +
                                (long long)B_ * HID_ + (long long)B_ * T_;
        convert_kernel<<<(int)((total + 255) / 256), 256, 0, stream>>>(
            m, emb, W_ih, W_hh, b_ih, b_hh, W_out,
            emb16, Wc16, Wout16, biasp, Hseq, tokperm);
    }

    // 2) PE table: emb @ W_ih^T + bias for all vocab rows (pp-packed)
    gemm_pe<<<dim3(VPAD_ / 128, G4H_ / 128), 256, 0, stream>>>(
        emb16, Wc16, biasp, PEx);

    // 3) entire recurrence in one persistent kernel (512 blocks, 2/CU)
    lstm_persistent<<<dim3(4, 128), 256, 0, stream>>>(
        PEx, tokperm, Wc16, Hseq, flags);

    // 4) out = Hseq[T] @ W_out^T + b_out
    gemm_out<<<dim3(B_ / 64, NIMG_ / 128), 256, 0, stream>>>(
        Hseq + (size_t)T_ * B_ * HID_, Wout16, b_out, out, NIMG_, HID_);
}

// Round 12
// 896.090 us; speedup vs baseline: 1.7497x; 1.7497x over previous
//
#include <hip/hip_runtime.h>
#include <cstdint>

#define B_    512
#define T_    64
#define VOCAB_ 10000
#define VPAD_ 10112     // vocab padded to 128
#define EMB_  512
#define HID_  1024
#define G4H_  4096      // 4*HID
#define KCAT_ 1536      // EMB + HID
#define NIMG_ 2048

typedef _Float16 half8 __attribute__((ext_vector_type(8)));
typedef _Float16 half4 __attribute__((ext_vector_type(4)));
typedef float floatx4 __attribute__((ext_vector_type(4)));

// Async global->LDS, 16B per lane. LDS dest = wave-uniform base (HW adds
// lane*16). Per-lane SOURCE address is free (gather OK).
__device__ __forceinline__ void async_copy16(void* lds_uniform, const void* gsrc) {
    __builtin_amdgcn_global_load_lds(
        (__attribute__((address_space(1))) void*)(uintptr_t)gsrc,
        (__attribute__((address_space(3))) void*)(uint32_t)(uintptr_t)lds_uniform,
        16, 0, 0);
}

__device__ __forceinline__ float fsig(float x)  { return 1.0f / (1.0f + __expf(-x)); }
__device__ __forceinline__ float ftanh(float x) { return 1.0f - 2.0f / (__expf(2.0f * x) + 1.0f); }

// Gate-interleaved weight-row permutation (R9):
//   n_perm = jblk*64 + gate*16 + jlo   <->   n_orig = gate*HID + (jblk*16 + jlo)

// ---------------------------------------------------------------------------
// One-time: emb->f16, Wc16 = permuted [W_ih|W_hh] (4096 x 1536), Wout16,
// biasp = permuted (b_ih+b_hh), Hseq[0] = 0, tokperm[t*B+b] = m[b][t].
// ---------------------------------------------------------------------------
__global__ __launch_bounds__(256) void convert_kernel(
    const int* __restrict__ m, const float* __restrict__ emb,
    const float* __restrict__ W_ih, const float* __restrict__ W_hh,
    const float* __restrict__ b_ih, const float* __restrict__ b_hh,
    const float* __restrict__ W_out,
    _Float16* __restrict__ emb16, _Float16* __restrict__ Wc16,
    _Float16* __restrict__ Wout16, float* __restrict__ biasp,
    _Float16* __restrict__ Hseq, int* __restrict__ tokperm)
{
    const long long EMB_N = (long long)VOCAB_ * EMB_;
    const long long WC_N  = (long long)G4H_ * KCAT_;
    const long long WO_N  = (long long)NIMG_ * HID_;
    const long long BI_N  = G4H_;
    const long long ST_N  = (long long)B_ * HID_;
    const long long TK_N  = (long long)B_ * T_;

    long long i = (long long)blockIdx.x * 256 + threadIdx.x;
    if (i < EMB_N) { emb16[i] = (_Float16)emb[i]; return; }
    i -= EMB_N;
    if (i < WC_N) {
        int n_perm = (int)(i / KCAT_);
        int k      = (int)(i % KCAT_);
        int gate = (n_perm >> 4) & 3;
        int j    = (n_perm >> 6) * 16 + (n_perm & 15);
        int n_orig = gate * HID_ + j;
        float v = (k < EMB_) ? W_ih[(size_t)n_orig * EMB_ + k]
                             : W_hh[(size_t)n_orig * HID_ + (k - EMB_)];
        Wc16[i] = (_Float16)v;
        return;
    }
    i -= WC_N;
    if (i < WO_N) { Wout16[i] = (_Float16)W_out[i]; return; }
    i -= WO_N;
    if (i < BI_N) {
        int n_perm = (int)i;
        int gate = (n_perm >> 4) & 3;
        int j    = (n_perm >> 6) * 16 + (n_perm & 15);
        biasp[i] = b_ih[gate * HID_ + j] + b_hh[gate * HID_ + j];
        return;
    }
    i -= BI_N;
    if (i < ST_N) { Hseq[i] = (_Float16)0.0f; return; }   // Hseq[0] = h_0 = 0
    i -= ST_N;
    if (i < TK_N) {
        int t = (int)(i / B_), b = (int)(i % B_);
        tokperm[i] = m[(size_t)b * T_ + t];
    }
}

// ---------------------------------------------------------------------------
// PE table GEMM: PEx[v][jblk*64 + jlo*4 + g] = emb[v] @ W_ih_perm^T + biasp
// (gate-packed: persistent kernel's acc-init is one 8B load per row).
// ---------------------------------------------------------------------------
__global__ __launch_bounds__(256) void gemm_pe(
    const _Float16* __restrict__ emb16, const _Float16* __restrict__ Wc16,
    const float* __restrict__ biasp, _Float16* __restrict__ PEx)
{
    __shared__ __align__(16) _Float16 As[128 * 32];
    __shared__ __align__(16) _Float16 Bs[128 * 32];

    const int tid  = threadIdx.x;
    const int wid  = tid >> 6;
    const int lane = tid & 63;
    const int lcol = lane & 15;
    const int quad = lane >> 4;
    const int wm   = wid >> 1;
    const int wn   = wid & 1;

    const int r0 = blockIdx.x * 128;
    const int n0 = blockIdx.y * 128;

    floatx4 acc[4][4];
#pragma unroll
    for (int i = 0; i < 4; ++i)
#pragma unroll
        for (int j = 0; j < 4; ++j) acc[i][j] = (floatx4){0.f, 0.f, 0.f, 0.f};

    const int ar = tid >> 2;
    const int kq = tid & 3;

    for (int k0 = 0; k0 < EMB_; k0 += 32) {
        async_copy16((char*)As + (wid << 10),
                     emb16 + (size_t)(r0 + ar) * EMB_ + (k0 + kq * 8));
        async_copy16((char*)As + 4096 + (wid << 10),
                     emb16 + (size_t)(r0 + 64 + ar) * EMB_ + (k0 + kq * 8));
        async_copy16((char*)Bs + (wid << 10),
                     Wc16 + (size_t)(n0 + ar) * KCAT_ + (k0 + kq * 8));
        async_copy16((char*)Bs + 4096 + (wid << 10),
                     Wc16 + (size_t)(n0 + 64 + ar) * KCAT_ + (k0 + kq * 8));
        __syncthreads();

        half8 af[4], bf[4];
#pragma unroll
        for (int mi = 0; mi < 4; ++mi)
            af[mi] = *(const half8*)&As[(wm * 64 + mi * 16 + lcol) * 32 + quad * 8];
#pragma unroll
        for (int ni = 0; ni < 4; ++ni)
            bf[ni] = *(const half8*)&Bs[(wn * 64 + ni * 16 + lcol) * 32 + quad * 8];
#pragma unroll
        for (int mi = 0; mi < 4; ++mi)
#pragma unroll
            for (int ni = 0; ni < 4; ++ni)
                acc[mi][ni] = __builtin_amdgcn_mfma_f32_16x16x32_f16(
                    af[mi], bf[ni], acc[mi][ni], 0, 0, 0);
        __syncthreads();
    }

    const int jblk = (n0 + wn * 64) >> 6;
    float bv[4];
#pragma unroll
    for (int ni = 0; ni < 4; ++ni) bv[ni] = biasp[n0 + wn * 64 + ni * 16 + lcol];
#pragma unroll
    for (int mi = 0; mi < 4; ++mi) {
#pragma unroll
        for (int r = 0; r < 4; ++r) {
            const int row = r0 + wm * 64 + mi * 16 + quad * 4 + r;
            half4 v;
#pragma unroll
            for (int ni = 0; ni < 4; ++ni)
                v[ni] = (_Float16)(acc[mi][ni][r] + bv[ni]);
            *(half4*)(PEx + (size_t)row * G4H_ + jblk * 64 + lcol * 4) = v;
        }
    }
}

// ---------------------------------------------------------------------------
// Persistent LSTM. Grid (4,64)=256 blocks, 1/CU (R10's 2/CU falsified: blocks
// are step-phase-locked, co-residency hides nothing and doubles traffic).
// R11 = R9 + (a) 4-PHASE interleaved waits: rot=(by&3)*8; quarter Qk (chunks
// 8k..8k+7) needs only producers by'=16k..16k+15; waits sit BETWEEN unrolled
// segments and are free once the ballot shows all bits. (b) coalesced h
// publish: LDS transpose -> one 8B relaxed-agent atomic store per thread
// (8x fewer write-through LLC transactions on the pre-flag drain path).
// Zero-fence freshness scheme (R7) kept byte-identical.
// ---------------------------------------------------------------------------
__global__ __launch_bounds__(256, 1) void lstm_persistent(
    const _Float16* __restrict__ PEx, const int* __restrict__ tokperm,
    const _Float16* __restrict__ Wc16,
    _Float16* __restrict__ Hseq,
    unsigned* __restrict__ flags)
{
    __shared__ __align__(16) char Wlds[131072];          // frag-major, 128 KB
    __shared__ __align__(16) _Float16 tbuf[4][16 * 20];  // per-wave transpose

    const int tid  = threadIdx.x;
    const int wid  = tid >> 6;
    const int lane = tid & 63;
    const int lcol = lane & 15;
    const int quad = lane >> 4;
    const int bx   = blockIdx.x;
    const int b0   = bx * 128;
    const int by   = blockIdx.y;
    const int n0   = by * 64;
    const int rot  = (by & 3) * 8;    // chunk rotation (wave-uniform)
    const int q0   = by & 3;          // starting quarter

    // One-time cross-launch safety: clear any stale lines (cheap, once).
    __builtin_amdgcn_fence(__ATOMIC_ACQUIRE, "agent");

    // ---- W one-time load, fragment-major: Wlds[((s*4+g)*64+lane)*16] holds
    // B-frag element W[n0+g*16+lcol][EMB + s*32+quad*8 ..+7]. Wave wid
    // handles s in [wid*8, wid*8+8). Conflict-free by construction.
    for (int si = 0; si < 8; ++si) {
        const int s = wid * 8 + si;
#pragma unroll
        for (int g = 0; g < 4; ++g) {
            half8 v = *(const half8*)(Wc16 + (size_t)(n0 + g * 16 + lcol) * KCAT_
                                      + EMB_ + s * 32 + quad * 8);
            *(half8*)(Wlds + (((s * 4 + g) << 6) + lane) * 16) = v;
        }
    }

    // Thread's outputs: rows wid*32+mi*16+quad*4+r (mi 0..1), col j=by*16+lcol
    float cst[2][4] = {{0.f, 0.f, 0.f, 0.f}, {0.f, 0.f, 0.f, 0.f}};
    half4 pe[2][4];

    // PE prefetch for t=0
#pragma unroll
    for (int mi = 0; mi < 2; ++mi)
#pragma unroll
        for (int r = 0; r < 4; ++r) {
            const int row = wid * 32 + mi * 16 + quad * 4 + r;
            const int tk = tokperm[b0 + row];
            pe[mi][r] = *(const half4*)(PEx + (size_t)tk * G4H_ + by * 64 + lcol * 4);
        }

    __syncthreads();  // W in LDS visible to all waves

    const int wrow = wid * 32;
    const int row16 = lane >> 2;   // epilogue store row (0..15)
    const int ch    = lane & 3;    // epilogue 8B chunk (4 j's)

    for (int t = 0; t < T_; ++t) {
        const _Float16* h_prev = Hseq + (size_t)t * (B_ * HID_);
        _Float16*       h_next = Hseq + (size_t)(t + 1) * (B_ * HID_);

        const unsigned want = 0x5AB00000u + (unsigned)(t - 1);
        const unsigned* f = flags + ((size_t)(t > 0 ? t - 1 : 0) * 4 + bx) * 64;

        unsigned long long rdy = (t == 0) ? ~0ull : 0ull;
        auto waitq = [&](int qq) {   // quarter qq: producers by' = 16qq..16qq+15
            const unsigned long long need = 0xFFFFull << (16 * qq);
            if ((rdy & need) == need) return;
            for (;;) {
                rdy = __ballot((int)(__hip_atomic_load(&f[lane], __ATOMIC_RELAXED,
                                                       __HIP_MEMORY_SCOPE_AGENT) == want));
                if ((rdy & need) == need) break;
                __builtin_amdgcn_s_sleep(1);
            }
            asm volatile("" ::: "memory");  // no hoisting of h loads above poll
        };

        // A-fragment source rows (plain cached loads on FRESH lines)
        const _Float16* arow0 = h_prev + (size_t)(b0 + wrow + lcol) * HID_ + quad * 8;
        const _Float16* arow1 = arow0 + (size_t)16 * HID_;

        floatx4 acc[2][4];
#pragma unroll
        for (int mi = 0; mi < 2; ++mi)
#pragma unroll
            for (int g = 0; g < 4; ++g)
#pragma unroll
                for (int r = 0; r < 4; ++r)
                    acc[mi][g][r] = (float)pe[mi][r][g];

        // ---- 4-phase pipeline: waits between straight-line segments ----
        waitq(q0);                       // chunks rot..rot+7
        half8 pa0[8], pa1[8];
#pragma unroll
        for (int c = 0; c < 8; ++c) {
            const int cs = (c + rot) & 31;
            pa0[c] = *(const half8*)(arow0 + cs * 32);
            pa1[c] = *(const half8*)(arow1 + cs * 32);
        }
        waitq((q0 + 1) & 3);             // chunks rot+8..rot+15 (prefetched s=0..7)

        auto kseg = [&](int sbeg, int send) {
#pragma unroll
            for (int s0 = 0; s0 < 32; ++s0) {   // full unroll; guard inside
                const int s = s0;
                if (s < sbeg || s >= send) continue;
                const int cs = (s + rot) & 31;
                const half8 a0 = pa0[s & 7];
                const half8 a1 = pa1[s & 7];
                if (s + 8 < 32) {
                    const int cs8 = (s + 8 + rot) & 31;
                    pa0[s & 7] = *(const half8*)(arow0 + cs8 * 32);
                    pa1[s & 7] = *(const half8*)(arow1 + cs8 * 32);
                }
#pragma unroll
                for (int g = 0; g < 4; ++g) {
                    const half8 bw = *(const half8*)(Wlds + (((cs * 4 + g) << 6) + lane) * 16);
                    acc[0][g] = __builtin_amdgcn_mfma_f32_16x16x32_f16(a0, bw, acc[0][g], 0, 0, 0);
                    acc[1][g] = __builtin_amdgcn_mfma_f32_16x16x32_f16(a1, bw, acc[1][g], 0, 0, 0);
                }
            }
        };

        kseg(0, 8);                      // uses Q(q0..q0+1); prefetches Q(q0+2)'s chunks? no:
                                         // s=0..7 prefetch chunks rot+8..15 = Q(q0+1) (waited)
        waitq((q0 + 2) & 3);             // s=8..15 prefetch chunks rot+16..23
        kseg(8, 16);
        waitq((q0 + 3) & 3);             // s=16..23 prefetch chunks rot+24..31
        kseg(16, 32);

        // ---- fused LSTM cell + LDS-transposed coalesced publish ----
        _Float16* tb = &tbuf[wid][0];
#pragma unroll
        for (int mi = 0; mi < 2; ++mi) {
#pragma unroll
            for (int r = 0; r < 4; ++r) {
                const float iv = fsig(acc[mi][0][r]);
                const float fv = fsig(acc[mi][1][r]);
                const float gv = ftanh(acc[mi][2][r]);
                const float ov = fsig(acc[mi][3][r]);
                cst[mi][r] = fv * cst[mi][r] + iv * gv;
                tb[(quad * 4 + r) * 20 + lcol] = (_Float16)(ov * ftanh(cst[mi][r]));
            }
            // wave-internal transpose read (compiler inserts lgkmcnt wait)
            half4 hv4 = *(const half4*)&tb[row16 * 20 + ch * 4];
            const int grow = wrow + mi * 16 + row16;
            unsigned long long bits = __builtin_bit_cast(unsigned long long, hv4);
            __hip_atomic_store(
                (unsigned long long*)&h_next[(size_t)(b0 + grow) * HID_ + by * 16 + ch * 4],
                bits, __ATOMIC_RELAXED, __HIP_MEMORY_SCOPE_AGENT);
        }

        // ---- publish: drain stores (syncthreads waits vmcnt 0), then one
        // relaxed flag store by tid0. NO fences. ----
        __syncthreads();
        if (tid == 0) {
            __hip_atomic_store(&flags[((size_t)t * 4 + bx) * 64 + by],
                               0x5AB00000u + (unsigned)t,
                               __ATOMIC_RELAXED, __HIP_MEMORY_SCOPE_AGENT);
        }

        // PE prefetch for t+1 (read-only cached data; overlaps others' polls)
        if (t + 1 < T_) {
#pragma unroll
            for (int mi = 0; mi < 2; ++mi)
#pragma unroll
                for (int r = 0; r < 4; ++r) {
                    const int row = wrow + mi * 16 + quad * 4 + r;
                    const int tk = tokperm[(t + 1) * B_ + b0 + row];
                    pe[mi][r] = *(const half4*)(PEx + (size_t)tk * G4H_ + by * 64 + lcol * 4);
                }
        }
    }
}

// ---------------------------------------------------------------------------
// Final projection GEMM (unpermuted): Out = h @ Wout16^T + b_out
// ---------------------------------------------------------------------------
__global__ __launch_bounds__(256) void gemm_out(
    const _Float16* __restrict__ A, const _Float16* __restrict__ Bw,
    const float* __restrict__ bias, float* __restrict__ Out, int N, int K)
{
    __shared__ __align__(16) _Float16 As[64 * 32];
    __shared__ __align__(16) _Float16 Bs[128 * 32];

    const int tid  = threadIdx.x;
    const int wid  = tid >> 6;
    const int lane = tid & 63;
    const int lcol = lane & 15;
    const int quad = lane >> 4;
    const int wm   = wid >> 1;
    const int wn   = wid & 1;

    const int b0 = blockIdx.x * 64;
    const int n0 = blockIdx.y * 128;

    floatx4 acc[2][4];
#pragma unroll
    for (int i = 0; i < 2; ++i)
#pragma unroll
        for (int j = 0; j < 4; ++j) acc[i][j] = (floatx4){0.f, 0.f, 0.f, 0.f};

    const int ar = tid >> 2;
    const int kq = tid & 3;

    for (int k0 = 0; k0 < K; k0 += 32) {
        async_copy16((char*)As + (wid << 10), A + (size_t)(b0 + ar) * K + (k0 + kq * 8));
        async_copy16((char*)Bs + (wid << 10), Bw + (size_t)(n0 + ar) * K + (k0 + kq * 8));
        async_copy16((char*)Bs + 4096 + (wid << 10),
                     Bw + (size_t)(n0 + 64 + ar) * K + (k0 + kq * 8));
        __syncthreads();

        half8 af[2], bfr[4];
#pragma unroll
        for (int mi = 0; mi < 2; ++mi)
            af[mi] = *(const half8*)&As[(wm * 32 + mi * 16 + lcol) * 32 + quad * 8];
#pragma unroll
        for (int ni = 0; ni < 4; ++ni)
            bfr[ni] = *(const half8*)&Bs[(wn * 64 + ni * 16 + lcol) * 32 + quad * 8];
#pragma unroll
        for (int mi = 0; mi < 2; ++mi)
#pragma unroll
            for (int ni = 0; ni < 4; ++ni)
                acc[mi][ni] = __builtin_amdgcn_mfma_f32_16x16x32_f16(
                    af[mi], bfr[ni], acc[mi][ni], 0, 0, 0);
        __syncthreads();
    }

#pragma unroll
    for (int mi = 0; mi < 2; ++mi) {
#pragma unroll
        for (int ni = 0; ni < 4; ++ni) {
            const int row = b0 + wm * 32 + mi * 16 + quad * 4;
            const int col = n0 + wn * 64 + ni * 16 + lcol;
            const float bv = bias[col];
#pragma unroll
            for (int r = 0; r < 4; ++r)
                Out[(size_t)(row + r) * N + col] = acc[mi][ni][r] + bv;
        }
    }
}

// ---------------------------------------------------------------------------
extern "C" void kernel_launch(void* const* d_in, const int* in_sizes, int n_in,
                              void* d_out, int out_size, void* d_ws, size_t ws_size,
                              hipStream_t stream)
{
    const int*   m     = (const int*)d_in[0];
    const float* emb   = (const float*)d_in[1];
    const float* W_ih  = (const float*)d_in[2];
    const float* W_hh  = (const float*)d_in[3];
    const float* b_ih  = (const float*)d_in[4];
    const float* b_hh  = (const float*)d_in[5];
    const float* W_out = (const float*)d_in[6];
    const float* b_out = (const float*)d_in[7];
    float* out = (float*)d_out;

    char* w = (char*)d_ws;
    size_t off = 0;
    auto alloc = [&](size_t bytes) {
        char* p = w + off;
        off = (off + bytes + 255) & ~(size_t)255;
        return p;
    };
    _Float16* emb16   = (_Float16*)alloc((size_t)VPAD_ * EMB_ * 2);
    _Float16* Wc16    = (_Float16*)alloc((size_t)G4H_ * KCAT_ * 2);
    _Float16* Wout16  = (_Float16*)alloc((size_t)NIMG_ * HID_ * 2);
    float*    biasp   = (float*)   alloc((size_t)G4H_ * 4);
    _Float16* Hseq    = (_Float16*)alloc((size_t)(T_ + 1) * B_ * HID_ * 2);  // 68 MB
    int*      tokperm = (int*)     alloc((size_t)B_ * T_ * 4);
    unsigned* flags   = (unsigned*)alloc((size_t)T_ * 4 * 64 * 4);   // 64 KB
    _Float16* PEx     = (_Float16*)alloc((size_t)VPAD_ * G4H_ * 2);  // 83 MB

    // 1) convert / permute / init (flags stay poisoned: magic differs per t)
    {
        const long long total = (long long)VOCAB_ * EMB_ + (long long)G4H_ * KCAT_ +
                                (long long)NIMG_ * HID_ + G4H_ +
                                (long long)B_ * HID_ + (long long)B_ * T_;
        convert_kernel<<<(int)((total + 255) / 256), 256, 0, stream>>>(
            m, emb, W_ih, W_hh, b_ih, b_hh, W_out,
            emb16, Wc16, Wout16, biasp, Hseq, tokperm);
    }

    // 2) PE table: emb @ W_ih^T + bias for all vocab rows (gate-packed)
    gemm_pe<<<dim3(VPAD_ / 128, G4H_ / 128), 256, 0, stream>>>(
        emb16, Wc16, biasp, PEx);

    // 3) entire recurrence in one persistent kernel (256 blocks, 1/CU)
    lstm_persistent<<<dim3(B_ / 128, G4H_ / 64), 256, 0, stream>>>(
        PEx, tokperm, Wc16, Hseq, flags);

    // 4) out = Hseq[T] @ W_out^T + b_out
    gemm_out<<<dim3(B_ / 64, NIMG_ / 128), 256, 0, stream>>>(
        Hseq + (size_t)T_ * B_ * HID_, Wout16, b_out, out, NIMG_, HID_);
}